// Round 9
// baseline (111.012 us; speedup 1.0000x reference)
//
#include <hip/hip_runtime.h>
#include <hip/hip_bf16.h>
#include <math.h>

#define Bsz 16
#define Nn  500
#define Deg 32
#define Hd  128
#define Pg  100
#define Etot 16000   // Nn*Deg
#define CHUNKS 64
#define ROWS_PER_CHUNK 250  // Etot / CHUNKS
#define NB_Z1   400          // 4 bps each, dispatched FIRST (overlap HBM stream)
#define NB_GT   64
#define NB_MEAN (Bsz * CHUNKS)   // 1024
#define TILE 16

// ============ K1: z1 (blocks 0..399) + GT prep (400..463) + mean partials (464..1487) ============
// z1[bp][r] = sum_t Wk[t,r] * qh[bp][t],  qh = Wq·fq1,  fq1 = WqL·le + WqV·(vis+le/500) + qf
// GT[u*128+r] = sum_t (sum_s WqG[s,u]*Wq[t,s]) * Wk[t,r]   (q_graph path, applied to mean in K2)
__global__ __launch_bounds__(256) void mega1(const float* __restrict__ emb,
                                             const float* __restrict__ wq,
                                             const float* __restrict__ wk,
                                             const float* __restrict__ wql,
                                             const float* __restrict__ wqv,
                                             const float* __restrict__ wqg,
                                             const float* __restrict__ qf,
                                             const float* __restrict__ vis,
                                             const float* __restrict__ le,
                                             float* __restrict__ partial,
                                             float* __restrict__ gt,
                                             float* __restrict__ z1g) {
    __shared__ __align__(16) char smem[18496];
    int blk = blockIdx.x;
    int tid = threadIdx.x;

    if (blk >= NB_Z1 + NB_GT) {
        // ---- mean partials (R5-proven) ----
        float4* red = (float4*)smem;
        int mb = blk - (NB_Z1 + NB_GT);
        int b = mb >> 6, chunk = mb & 63;
        int rgrp = tid >> 5, c4 = tid & 31;
        const float4* base = (const float4*)(emb + (size_t)b * Etot * Hd);
        int e0 = chunk * ROWS_PER_CHUNK;
        float4 acc = make_float4(0.f, 0.f, 0.f, 0.f);
        for (int e = e0 + rgrp; e < e0 + ROWS_PER_CHUNK; e += 8) {
            float4 v = base[(size_t)e * 32 + c4];
            acc.x += v.x; acc.y += v.y; acc.z += v.z; acc.w += v.w;
        }
        red[tid] = acc;
        __syncthreads();
        for (int s = 128; s >= 32; s >>= 1) {
            if (tid < s) {
                float4 a = red[tid], o = red[tid + s];
                a.x += o.x; a.y += o.y; a.z += o.z; a.w += o.w;
                red[tid] = a;
            }
            __syncthreads();
        }
        if (tid < 32)
            ((float4*)partial)[((size_t)b * CHUNKS + chunk) * 32 + tid] = red[tid];
        return;
    }

    if (blk >= NB_Z1) {
        // ---- GT prep (R5-proven f==2 branch) ----
        float (*wv_s)[Hd] = (float (*)[Hd])smem;
        int h = tid >> 7, r = tid & 127;
        int u = (((blk - NB_Z1)) << 1) | h;
        float acc1 = 0.f;
#pragma unroll 8
        for (int s = 0; s < Hd; ++s)
            acc1 += wqg[s * Hd + u] * wq[r * Hd + s];
        wv_s[h][r] = acc1;
        __syncthreads();
        float acc = 0.f;
#pragma unroll 8
        for (int tt = 0; tt < Hd; ++tt)
            acc += wv_s[h][tt] * wk[tt * Hd + r];
        gt[u * Hd + r] = acc;
        return;
    }

    // ---- z1 blocks: 4 bps each, tiled-LDS matvec chain ----
    {
        float* wt   = (float*)smem;          // [TILE][129]
        float* le_s = wt + TILE * 129;       // [4][128]
        float* vi_s = le_s + 512;
        float* qf_s = vi_s + 512;
        float* fq_s = qf_s + 512;
        float* qh_s = fq_s + 512;

        int unit = blk;
        int b = unit / 25, p0 = (unit % 25) * 4;
        int bp0 = b * Pg + p0;

        // stage inputs (coalesced)
        for (int i = tid; i < 512; i += 256) {
            int bp = i >> 7, c = i & 127;
            size_t off = (size_t)(bp0 + bp) * Hd + c;
            float l = le[off];
            le_s[i] = l;
            vi_s[i] = vis[off] + l * (1.f / (float)Nn);
            qf_s[i] = qf[off];
        }
        __syncthreads();

        int t = tid & 127, g = tid >> 7;
        int x0o = (2 * g) * 128, x1o = (2 * g + 1) * 128;

        // phase 1: fq1 = WqL·le + WqV·vis' + qf
        float a0 = 0.f, a1 = 0.f;
        for (int k = 0; k < Hd / TILE; ++k) {
            // WqL tile
            for (int i = tid; i < Hd * TILE; i += 256) {
                int row = i >> 4, s = i & (TILE - 1);
                wt[s * 129 + row] = wql[row * Hd + k * TILE + s];
            }
            __syncthreads();
#pragma unroll
            for (int s = 0; s < TILE; ++s) {
                float w = wt[s * 129 + t];
                a0 += w * le_s[x0o + k * TILE + s];
                a1 += w * le_s[x1o + k * TILE + s];
            }
            __syncthreads();
            // WqV tile
            for (int i = tid; i < Hd * TILE; i += 256) {
                int row = i >> 4, s = i & (TILE - 1);
                wt[s * 129 + row] = wqv[row * Hd + k * TILE + s];
            }
            __syncthreads();
#pragma unroll
            for (int s = 0; s < TILE; ++s) {
                float w = wt[s * 129 + t];
                a0 += w * vi_s[x0o + k * TILE + s];
                a1 += w * vi_s[x1o + k * TILE + s];
            }
            __syncthreads();
        }
        fq_s[x0o + t] = a0 + qf_s[x0o + t];
        fq_s[x1o + t] = a1 + qf_s[x1o + t];
        __syncthreads();

        // phase 2: qh = Wq · fq1
        a0 = a1 = 0.f;
        for (int k = 0; k < Hd / TILE; ++k) {
            for (int i = tid; i < Hd * TILE; i += 256) {
                int row = i >> 4, s = i & (TILE - 1);
                wt[s * 129 + row] = wq[row * Hd + k * TILE + s];
            }
            __syncthreads();
#pragma unroll
            for (int s = 0; s < TILE; ++s) {
                float w = wt[s * 129 + t];
                a0 += w * fq_s[x0o + k * TILE + s];
                a1 += w * fq_s[x1o + k * TILE + s];
            }
            __syncthreads();
        }
        qh_s[x0o + t] = a0;
        qh_s[x1o + t] = a1;
        __syncthreads();

        // phase 3: z1 = Wk^T · qh  (naturally coalesced)
        float z0 = 0.f, z1a = 0.f;
#pragma unroll 4
        for (int u = 0; u < Hd; ++u) {
            float w = wk[u * Hd + t];
            z0  += w * qh_s[x0o + u];
            z1a += w * qh_s[x1o + u];
        }
        z1g[(size_t)(bp0 + 2 * g) * Hd + t]     = z0;
        z1g[(size_t)(bp0 + 2 * g + 1) * Hd + t] = z1a;
    }
}

// ============ K2: gz + z=z1+gz + gather/write/dot + softmax (R5-proven skeleton) ============
__global__ __launch_bounds__(256) void decode_z(const float* __restrict__ partial,
                                                const float* __restrict__ gt,
                                                const float* __restrict__ z1g,
                                                const float* __restrict__ emb,
                                                const float* __restrict__ dists,
                                                const float* __restrict__ pref,
                                                const int* __restrict__ indices,
                                                const int* __restrict__ lni_arr,
                                                const float* __restrict__ gmask,
                                                float* __restrict__ out_probs,
                                                float* __restrict__ out_nk,
                                                float* __restrict__ out_og) {
    int blk = blockIdx.x;
    int b = blk / 25, p0 = (blk % 25) * 4;
    int bp0 = b * Pg + p0;
    int tid = threadIdx.x;

    __shared__ int lni_s[4];
    __shared__ float ps[2][Hd];
    __shared__ float mean_s[Hd];
    __shared__ float gzp[2][Hd];
    __shared__ __align__(16) float z_s[4][Hd];
    __shared__ float score_s[4][Deg];

    if (tid < 4) lni_s[tid] = lni_arr[bp0 + tid];
    __syncthreads();

    // Prefetch scattered softmax inputs into registers
    int bp_i = tid >> 5, d = tid & 31;
    int nk = 0; float2 dd = make_float2(0.f, 0.f); float mval = 0.f;
    if (tid < 128) {
        int lnv = lni_s[bp_i];
        nk = indices[(((size_t)b * Etot) + (size_t)lnv * Deg + d) * 2 + 1];
        out_nk[(size_t)(bp0 + bp_i) * Deg + d] = (float)nk;
        dd = *(const float2*)(dists + (((size_t)b * Nn + (size_t)lnv) * Nn + nk) * 2);
        mval = gmask[(size_t)(bp0 + bp_i) * Nn + nk];
    }
    float p0v = pref[0], p1v = pref[1];

    // partial-reduce for this b (32 KB, L2-resident)
    {
        int c = tid & 127, h = tid >> 7;
        float s = 0.f;
        const float* pb = partial + (size_t)b * CHUNKS * Hd;
        for (int k = h * 32; k < h * 32 + 32; ++k)
            s += pb[k * Hd + c];
        ps[h][c] = s;
    }
    __syncthreads();
    if (tid < Hd)
        mean_s[tid] = (ps[0][tid] + ps[1][tid]) * (1.f / (float)Etot);
    __syncthreads();

    // gz = GT·mean (half-split over u), then z = z1 + gz
    {
        int r = tid & 127, h = tid >> 7;
        float acc = 0.f;
        const float* gtp = gt + r;
#pragma unroll 4
        for (int u = h * 64; u < h * 64 + 64; ++u)
            acc += gtp[u * Hd] * mean_s[u];
        gzp[h][r] = acc;
    }
    __syncthreads();
    for (int i = tid; i < 512; i += 256) {
        int bp = i >> 7, r = i & 127;
        z_s[bp][r] = z1g[(size_t)(bp0 + bp) * Hd + r] + gzp[0][r] + gzp[1][r];
    }
    __syncthreads();

    // gather og from emb (L3-hot), copy out, dot with z — R5-proven interleaved loop
    {
        int rg = tid >> 5, c4 = tid & 31;
        for (int bp = 0; bp < 4; ++bp) {
            const float4* ebase = (const float4*)emb + ((size_t)b * Etot + (size_t)lni_s[bp] * Deg) * 32;
            float4* ob = (float4*)out_og + ((size_t)(bp0 + bp)) * (Deg * 32);
            float4 z4 = ((const float4*)z_s[bp])[c4];
#pragma unroll
            for (int r0 = 0; r0 < 4; ++r0) {
                int r = rg + r0 * 8;
                float4 v = ebase[r * 32 + c4];
                ob[r * 32 + c4] = v;
                float part = v.x * z4.x + v.y * z4.y + v.z * z4.z + v.w * z4.w;
                for (int m = 16; m >= 1; m >>= 1)
                    part += __shfl_xor(part, m, 64);
                if (c4 == 0) score_s[bp][r] = part;
            }
        }
    }
    __syncthreads();

    // softmax over Deg for the 4 bps (threads 0..127 = 4x32)
    if (tid < 128) {
        float s = score_s[bp_i][d] * 0.011048543456039805f;  // 1/(8*sqrt(128))
        float ds = p0v * dd.x + p1v * dd.y;
        s -= ds * 0.7071067811865476f;                       // /sqrt(2)
        float sc = 10.0f * tanhf(s);
        float m = mval;
        if (isinf(m) && m < 0.f) m = -1.0e8f;
        float v = sc + m;
        float mx = v;
        for (int mm = 16; mm >= 1; mm >>= 1)
            mx = fmaxf(mx, __shfl_xor(mx, mm, 64));
        float e = expf(v - mx);
        float sum = e;
        for (int mm = 16; mm >= 1; mm >>= 1)
            sum += __shfl_xor(sum, mm, 64);
        out_probs[(size_t)(bp0 + bp_i) * Deg + d] = e / sum;
    }
}

extern "C" void kernel_launch(void* const* d_in, const int* in_sizes, int n_in,
                              void* d_out, int out_size, void* d_ws, size_t ws_size,
                              hipStream_t stream) {
    const float* emb       = (const float*)d_in[0];
    const float* dists     = (const float*)d_in[1];
    const float* pref      = (const float*)d_in[2];
    const int*   indices   = (const int*)d_in[3];
    // d_in[4] = Wq_first : unused by the reference
    const float* Wq_last    = (const float*)d_in[5];
    const float* Wq_visited = (const float*)d_in[6];
    const float* Wq_graph   = (const float*)d_in[7];
    const float* Wq         = (const float*)d_in[8];
    const float* Wk         = (const float*)d_in[9];
    const float* q_first    = (const float*)d_in[10];
    const float* visited    = (const float*)d_in[11];
    const float* last_edge  = (const float*)d_in[12];
    const int*   lni        = (const int*)d_in[13];
    const float* gmask      = (const float*)d_in[14];

    float* w = (float*)d_ws;
    float* ws_partial = w;                                       // 16*64*128 = 131072
    float* ws_gt      = ws_partial + (size_t)Bsz * CHUNKS * Hd;  // 16384
    float* ws_z1      = ws_gt + Hd * Hd;                         // 204800

    float* out       = (float*)d_out;
    float* out_probs = out;
    float* out_nk    = out + (size_t)Bsz * Pg * Deg;
    float* out_og    = out + 2 * (size_t)Bsz * Pg * Deg;

    mega1<<<NB_Z1 + NB_GT + NB_MEAN, 256, 0, stream>>>(emb, Wq, Wk, Wq_last, Wq_visited,
                                                       Wq_graph, q_first, visited, last_edge,
                                                       ws_partial, ws_gt, ws_z1);
    decode_z<<<400, 256, 0, stream>>>(ws_partial, ws_gt, ws_z1, emb, dists, pref,
                                      indices, lni, gmask, out_probs, out_nk, out_og);
}

// Round 10
// 47.095 us; speedup vs baseline: 2.3572x; 2.3572x over previous
//
#include <hip/hip_runtime.h>
#include <hip/hip_bf16.h>
#include <math.h>

#define Bsz 16
#define Nn  500
#define Deg 32
#define Hd  128
#define Pg  100
#define Etot 16000   // Nn*Deg
#define CHUNKS 64
#define ROWS_PER_CHUNK 250  // Etot / CHUNKS
#define PREP_BLKS 256       // 64 MT + 64 AT + 64 BT + 64 GT

// ============ K1: all weight prep (blocks 0..255) + mean partials (256..1279) ============
// (R5-proven fused_all, unchanged)
__global__ __launch_bounds__(256) void fused_all(const float* __restrict__ emb,
                                                 const float* __restrict__ wq,
                                                 const float* __restrict__ wk,
                                                 const float* __restrict__ wql,
                                                 const float* __restrict__ wqv,
                                                 const float* __restrict__ wqg,
                                                 float* __restrict__ partial,
                                                 float* __restrict__ mt,
                                                 float* __restrict__ at,
                                                 float* __restrict__ bt,
                                                 float* __restrict__ gt) {
    int blk = blockIdx.x;
    int tid = threadIdx.x;
    __shared__ float4 red[256];
    __shared__ float wv_s[2][Hd];

    if (blk >= PREP_BLKS) {
        int mb = blk - PREP_BLKS;
        int b = mb >> 6, chunk = mb & 63;
        int rgrp = tid >> 5, c4 = tid & 31;
        const float4* base = (const float4*)(emb + (size_t)b * Etot * Hd);
        int e0 = chunk * ROWS_PER_CHUNK;
        float4 acc = make_float4(0.f, 0.f, 0.f, 0.f);
        for (int e = e0 + rgrp; e < e0 + ROWS_PER_CHUNK; e += 8) {
            float4 v = base[(size_t)e * 32 + c4];
            acc.x += v.x; acc.y += v.y; acc.z += v.z; acc.w += v.w;
        }
        red[tid] = acc;
        __syncthreads();
        for (int s = 128; s >= 32; s >>= 1) {
            if (tid < s) {
                float4 a = red[tid], o = red[tid + s];
                a.x += o.x; a.y += o.y; a.z += o.z; a.w += o.w;
                red[tid] = a;
            }
            __syncthreads();
        }
        if (tid < 32)
            ((float4*)partial)[((size_t)b * CHUNKS + chunk) * 32 + tid] = red[tid];
        return;
    }

    int h = tid >> 7;
    int r = tid & 127;
    if (blk < 64) {
        int s = (blk << 1) | h;
        float acc = 0.f;
#pragma unroll 8
        for (int t = 0; t < Hd; ++t)
            acc += wq[t * Hd + s] * wk[t * Hd + r];
        mt[s * Hd + r] = acc;
        return;
    }
    int f = (blk - 64) >> 6;                 // 0=AT 1=BT 2=GT
    int u = (((blk - 64) & 63) << 1) | h;
    int t = r;
    float acc1 = 0.f;
    if (f == 0) {
#pragma unroll 8
        for (int s = 0; s < Hd; ++s)
            acc1 += (wql[s * Hd + u] + wqv[s * Hd + u] * (1.f / (float)Nn)) * wq[t * Hd + s];
    } else if (f == 1) {
#pragma unroll 8
        for (int s = 0; s < Hd; ++s)
            acc1 += wqv[s * Hd + u] * wq[t * Hd + s];
    } else {
#pragma unroll 8
        for (int s = 0; s < Hd; ++s)
            acc1 += wqg[s * Hd + u] * wq[t * Hd + s];
    }
    wv_s[h][t] = acc1;
    __syncthreads();
    float acc = 0.f;
#pragma unroll 8
    for (int tt = 0; tt < Hd; ++tt)
        acc += wv_s[h][tt] * wk[tt * Hd + r];
    float* dst = (f == 0) ? at : (f == 1) ? bt : gt;
    dst[u * Hd + r] = acc;
}

// ============ K2: R5's decode_z at 2 bps/block (800 blocks) for 2x latency hiding ============
__global__ __launch_bounds__(256) void decode_z(const float* __restrict__ partial,
                                                const float* __restrict__ gt,
                                                const float* __restrict__ at,
                                                const float* __restrict__ bt,
                                                const float* __restrict__ mt,
                                                const float* __restrict__ qf,
                                                const float* __restrict__ vis,
                                                const float* __restrict__ le,
                                                const float* __restrict__ emb,
                                                const float* __restrict__ dists,
                                                const float* __restrict__ pref,
                                                const int* __restrict__ indices,
                                                const int* __restrict__ lni_arr,
                                                const float* __restrict__ gmask,
                                                float* __restrict__ out_probs,
                                                float* __restrict__ out_nk,
                                                float* __restrict__ out_og) {
    int blk = blockIdx.x;
    int b = blk / 50, p0 = (blk % 50) * 2;
    int bp0 = b * Pg + p0;
    int tid = threadIdx.x;

    __shared__ int lni_s[2];
    __shared__ float ps[2][Hd];
    __shared__ float mean_s[Hd];
    __shared__ __align__(16) float ins[Hd][3][2];   // [u][m][bp]  m: 0=le 1=vis 2=qf
    __shared__ float zpart[2][2][Hd];
    __shared__ __align__(16) float z_s[2][Hd];
    __shared__ float score_s[2][Deg];

    if (tid < 2) lni_s[tid] = lni_arr[bp0 + tid];
    __syncthreads();

    // Prefetch scattered softmax inputs into registers (fly under z phase)
    int bp_i = tid >> 5, d = tid & 31;
    int nk = 0; float2 dd = make_float2(0.f, 0.f); float mval = 0.f;
    if (tid < 64) {
        int lnv = lni_s[bp_i];
        nk = indices[(((size_t)b * Etot) + (size_t)lnv * Deg + d) * 2 + 1];
        out_nk[(size_t)(bp0 + bp_i) * Deg + d] = (float)nk;
        dd = *(const float2*)(dists + (((size_t)b * Nn + (size_t)lnv) * Nn + nk) * 2);
        mval = gmask[(size_t)(bp0 + bp_i) * Nn + nk];
    }
    float p0v = pref[0], p1v = pref[1];

    // ---- partial-reduce for this b (redundant per block; L2-resident, 32 KB) ----
    {
        int c = tid & 127, h = tid >> 7;
        float s = 0.f;
        const float* pb = partial + (size_t)b * CHUNKS * Hd;
        for (int k = h * 32; k < h * 32 + 32; ++k)
            s += pb[k * Hd + c];
        ps[h][c] = s;
    }
    // ---- stage le/vis/qf for 2 bps into transposed LDS ----
    if (tid < 192) {
        size_t base4 = (size_t)bp0 * 32;
        const float4* le4 = (const float4*)le + base4;
        const float4* vi4 = (const float4*)vis + base4;
        const float4* qf4 = (const float4*)qf + base4;
        int m = tid / 64, idx = tid & 63;          // 3 arrays x (2bp x 32 c4)
        int bp = idx >> 5, cc4 = idx & 31;
        float4 v = (m == 0) ? le4[idx] : (m == 1) ? vi4[idx] : qf4[idx];
        int u0 = cc4 * 4;
        ins[u0 + 0][m][bp] = v.x;
        ins[u0 + 1][m][bp] = v.y;
        ins[u0 + 2][m][bp] = v.z;
        ins[u0 + 3][m][bp] = v.w;
    }
    __syncthreads();
    if (tid < Hd)
        mean_s[tid] = (ps[0][tid] + ps[1][tid]) * (1.f / (float)Etot);
    __syncthreads();

    // ---- z for 2 bps: half-split over u ----
    {
        int r = tid & 127, h = tid >> 7;
        float acc0 = 0.f, acc1 = 0.f, accg = 0.f;
        const float* atp = at + r;
        const float* btp = bt + r;
        const float* mtp = mt + r;
        const float* gtp = gt + r;
#pragma unroll 4
        for (int u = h * 64; u < h * 64 + 64; ++u) {
            float wa = atp[u * Hd];
            float wb = btp[u * Hd];
            float wm = mtp[u * Hd];
            float wg = gtp[u * Hd];
            accg += wg * mean_s[u];
            float lv0 = ins[u][0][0], lv1 = ins[u][0][1];
            float vv0 = ins[u][1][0], vv1 = ins[u][1][1];
            float qv0 = ins[u][2][0], qv1 = ins[u][2][1];
            acc0 += wa * lv0 + wb * vv0 + wm * qv0;
            acc1 += wa * lv1 + wb * vv1 + wm * qv1;
        }
        zpart[h][0][r] = acc0 + accg;
        zpart[h][1][r] = acc1 + accg;
    }
    __syncthreads();
    {
        int bp = tid >> 7, r = tid & 127;
        z_s[bp][r] = zpart[0][bp][r] + zpart[1][bp][r];
    }
    __syncthreads();

    // ---- gather og from emb (L3-hot), copy out, dot with z (R5-proven interleave) ----
    {
        int rg = tid >> 5, c4 = tid & 31;
        for (int bp = 0; bp < 2; ++bp) {
            const float4* ebase = (const float4*)emb + ((size_t)b * Etot + (size_t)lni_s[bp] * Deg) * 32;
            float4* ob = (float4*)out_og + ((size_t)(bp0 + bp)) * (Deg * 32);
            float4 z4 = ((const float4*)z_s[bp])[c4];
#pragma unroll
            for (int r0 = 0; r0 < 4; ++r0) {
                int r = rg + r0 * 8;
                float4 v = ebase[r * 32 + c4];
                ob[r * 32 + c4] = v;
                float part = v.x * z4.x + v.y * z4.y + v.z * z4.z + v.w * z4.w;
                for (int m = 16; m >= 1; m >>= 1)
                    part += __shfl_xor(part, m, 64);
                if (c4 == 0) score_s[bp][r] = part;
            }
        }
    }
    __syncthreads();

    // ---- softmax over Deg for the 2 bps (threads 0..63 = 2x32) ----
    if (tid < 64) {
        float s = score_s[bp_i][d] * 0.011048543456039805f;  // 1/(8*sqrt(128))
        float ds = p0v * dd.x + p1v * dd.y;
        s -= ds * 0.7071067811865476f;                       // /sqrt(2)
        float sc = 10.0f * tanhf(s);
        float m = mval;
        if (isinf(m) && m < 0.f) m = -1.0e8f;
        float v = sc + m;
        float mx = v;
        for (int mm = 16; mm >= 1; mm >>= 1)
            mx = fmaxf(mx, __shfl_xor(mx, mm, 64));
        float e = expf(v - mx);
        float sum = e;
        for (int mm = 16; mm >= 1; mm >>= 1)
            sum += __shfl_xor(sum, mm, 64);
        out_probs[(size_t)(bp0 + bp_i) * Deg + d] = e / sum;
    }
}

extern "C" void kernel_launch(void* const* d_in, const int* in_sizes, int n_in,
                              void* d_out, int out_size, void* d_ws, size_t ws_size,
                              hipStream_t stream) {
    const float* emb       = (const float*)d_in[0];
    const float* dists     = (const float*)d_in[1];
    const float* pref      = (const float*)d_in[2];
    const int*   indices   = (const int*)d_in[3];
    // d_in[4] = Wq_first : unused by the reference
    const float* Wq_last    = (const float*)d_in[5];
    const float* Wq_visited = (const float*)d_in[6];
    const float* Wq_graph   = (const float*)d_in[7];
    const float* Wq         = (const float*)d_in[8];
    const float* Wk         = (const float*)d_in[9];
    const float* q_first    = (const float*)d_in[10];
    const float* visited    = (const float*)d_in[11];
    const float* last_edge  = (const float*)d_in[12];
    const int*   lni        = (const int*)d_in[13];
    const float* gmask      = (const float*)d_in[14];

    float* w = (float*)d_ws;
    float* ws_partial = w;                                       // 16*64*128
    float* ws_mt      = ws_partial + (size_t)Bsz * CHUNKS * Hd;
    float* ws_at      = ws_mt + Hd * Hd;
    float* ws_bt      = ws_at + Hd * Hd;
    float* ws_gt      = ws_bt + Hd * Hd;

    float* out       = (float*)d_out;
    float* out_probs = out;
    float* out_nk    = out + (size_t)Bsz * Pg * Deg;
    float* out_og    = out + 2 * (size_t)Bsz * Pg * Deg;

    fused_all<<<PREP_BLKS + Bsz * CHUNKS, 256, 0, stream>>>(emb, Wq, Wk, Wq_last, Wq_visited,
                                                            Wq_graph, ws_partial, ws_mt,
                                                            ws_at, ws_bt, ws_gt);
    decode_z<<<800, 256, 0, stream>>>(ws_partial, ws_gt, ws_at, ws_bt, ws_mt,
                                      q_first, visited, last_edge, emb, dists, pref,
                                      indices, lni, gmask, out_probs, out_nk, out_og);
}

// Round 11
// 45.387 us; speedup vs baseline: 2.4459x; 1.0376x over previous
//
#include <hip/hip_runtime.h>
#include <hip/hip_bf16.h>
#include <math.h>

#define Bsz 16
#define Nn  500
#define Deg 32
#define Hd  128
#define Pg  100
#define Etot 16000   // Nn*Deg
#define CHUNKS 64
#define ROWS_PER_CHUNK 250  // Etot / CHUNKS
#define PREP_BLKS 128       // 64 P1(AT,BT) + 64 P2(MT,GT)

__device__ __forceinline__ unsigned pack_bf2(float a, float b) {
    unsigned ua = (__float_as_uint(a) + 0x8000u) >> 16;
    unsigned ub = (__float_as_uint(b) + 0x8000u) & 0xffff0000u;
    return ua | ub;
}

// ============ K1: packed weight prep (blocks 0..127) + mean partials (128..1151) ============
// P1[u*128+r] = pack_bf16(AT[u][r], BT[u][r]);  P2[u*128+r] = pack_bf16(MT[u][r], GT[u][r])
// AT[u,r] = sum_t (sum_s (WqL[s,u]+WqV[s,u]/500)*Wq[t,s]) * Wk[t,r]
// BT[u,r] = same with WqV;  GT[u,r] = same with WqG;  MT[u,r] = sum_t Wq[t,u]*Wk[t,r]
__global__ __launch_bounds__(256) void fused_all(const float* __restrict__ emb,
                                                 const float* __restrict__ wq,
                                                 const float* __restrict__ wk,
                                                 const float* __restrict__ wql,
                                                 const float* __restrict__ wqv,
                                                 const float* __restrict__ wqg,
                                                 float* __restrict__ partial,
                                                 unsigned* __restrict__ p1,
                                                 unsigned* __restrict__ p2) {
    int blk = blockIdx.x;
    int tid = threadIdx.x;
    __shared__ float4 red[256];
    __shared__ float wv_s[4][Hd];   // [0..1]=A halves, [2..3]=B/G halves

    if (blk >= PREP_BLKS) {
        // ---- mean partials (R5/R10-proven) ----
        int mb = blk - PREP_BLKS;
        int b = mb >> 6, chunk = mb & 63;
        int rgrp = tid >> 5, c4 = tid & 31;
        const float4* base = (const float4*)(emb + (size_t)b * Etot * Hd);
        int e0 = chunk * ROWS_PER_CHUNK;
        float4 acc = make_float4(0.f, 0.f, 0.f, 0.f);
        for (int e = e0 + rgrp; e < e0 + ROWS_PER_CHUNK; e += 8) {
            float4 v = base[(size_t)e * 32 + c4];
            acc.x += v.x; acc.y += v.y; acc.z += v.z; acc.w += v.w;
        }
        red[tid] = acc;
        __syncthreads();
        for (int s = 128; s >= 32; s >>= 1) {
            if (tid < s) {
                float4 a = red[tid], o = red[tid + s];
                a.x += o.x; a.y += o.y; a.z += o.z; a.w += o.w;
                red[tid] = a;
            }
            __syncthreads();
        }
        if (tid < 32)
            ((float4*)partial)[((size_t)b * CHUNKS + chunk) * 32 + tid] = red[tid];
        return;
    }

    int h = tid >> 7;        // which u-row of this block
    int r = tid & 127;       // stage-1 index t = r; stage-2 output col = r
    if (blk < 64) {
        // ---- P1 = (AT, BT) ----
        int u = (blk << 1) | h;
        float accA = 0.f, accB = 0.f;
#pragma unroll 8
        for (int s = 0; s < Hd; ++s) {
            float q = wq[r * Hd + s];
            float wv = wqv[s * Hd + u];
            accA += (wql[s * Hd + u] + wv * (1.f / (float)Nn)) * q;
            accB += wv * q;
        }
        wv_s[h][r] = accA;
        wv_s[2 + h][r] = accB;
        __syncthreads();
        float a2 = 0.f, b2 = 0.f;
#pragma unroll 8
        for (int tt = 0; tt < Hd; ++tt) {
            float wkv = wk[tt * Hd + r];
            a2 += wv_s[h][tt] * wkv;
            b2 += wv_s[2 + h][tt] * wkv;
        }
        p1[u * Hd + r] = pack_bf2(a2, b2);
        return;
    }
    {
        // ---- P2 = (MT, GT) ----
        int u = ((blk - 64) << 1) | h;
        float accG = 0.f;
#pragma unroll 8
        for (int s = 0; s < Hd; ++s)
            accG += wqg[s * Hd + u] * wq[r * Hd + s];
        wv_s[h][r] = accG;
        __syncthreads();
        float m2 = 0.f, g2 = 0.f;
#pragma unroll 8
        for (int tt = 0; tt < Hd; ++tt) {
            float wkv = wk[tt * Hd + r];
            m2 += wq[tt * Hd + u] * wkv;
            g2 += wv_s[h][tt] * wkv;
        }
        p2[u * Hd + r] = pack_bf2(m2, g2);
    }
}

// ============ K2: R10's decode_z (800 blocks x 2 bps) with packed-bf16 weight loads ============
__global__ __launch_bounds__(256) void decode_z(const float* __restrict__ partial,
                                                const unsigned* __restrict__ p1,
                                                const unsigned* __restrict__ p2,
                                                const float* __restrict__ qf,
                                                const float* __restrict__ vis,
                                                const float* __restrict__ le,
                                                const float* __restrict__ emb,
                                                const float* __restrict__ dists,
                                                const float* __restrict__ pref,
                                                const int* __restrict__ indices,
                                                const int* __restrict__ lni_arr,
                                                const float* __restrict__ gmask,
                                                float* __restrict__ out_probs,
                                                float* __restrict__ out_nk,
                                                float* __restrict__ out_og) {
    int blk = blockIdx.x;
    int b = blk / 50, p0 = (blk % 50) * 2;
    int bp0 = b * Pg + p0;
    int tid = threadIdx.x;

    __shared__ int lni_s[2];
    __shared__ float ps[2][Hd];
    __shared__ float mean_s[Hd];
    __shared__ __align__(16) float ins[Hd][3][2];   // [u][m][bp]  m: 0=le 1=vis 2=qf
    __shared__ float zpart[2][2][Hd];
    __shared__ __align__(16) float z_s[2][Hd];
    __shared__ float score_s[2][Deg];

    if (tid < 2) lni_s[tid] = lni_arr[bp0 + tid];
    __syncthreads();

    // Prefetch scattered softmax inputs into registers (fly under z phase)
    int bp_i = tid >> 5, d = tid & 31;
    int nk = 0; float2 dd = make_float2(0.f, 0.f); float mval = 0.f;
    if (tid < 64) {
        int lnv = lni_s[bp_i];
        nk = indices[(((size_t)b * Etot) + (size_t)lnv * Deg + d) * 2 + 1];
        out_nk[(size_t)(bp0 + bp_i) * Deg + d] = (float)nk;
        dd = *(const float2*)(dists + (((size_t)b * Nn + (size_t)lnv) * Nn + nk) * 2);
        mval = gmask[(size_t)(bp0 + bp_i) * Nn + nk];
    }
    float p0v = pref[0], p1v = pref[1];

    // ---- partial-reduce for this b (redundant per block; L2-resident, 32 KB) ----
    {
        int c = tid & 127, h = tid >> 7;
        float s = 0.f;
        const float* pb = partial + (size_t)b * CHUNKS * Hd;
        for (int k = h * 32; k < h * 32 + 32; ++k)
            s += pb[k * Hd + c];
        ps[h][c] = s;
    }
    // ---- stage le/vis/qf for 2 bps into transposed LDS ----
    if (tid < 192) {
        size_t base4 = (size_t)bp0 * 32;
        const float4* le4 = (const float4*)le + base4;
        const float4* vi4 = (const float4*)vis + base4;
        const float4* qf4 = (const float4*)qf + base4;
        int m = tid / 64, idx = tid & 63;
        int bp = idx >> 5, cc4 = idx & 31;
        float4 v = (m == 0) ? le4[idx] : (m == 1) ? vi4[idx] : qf4[idx];
        int u0 = cc4 * 4;
        ins[u0 + 0][m][bp] = v.x;
        ins[u0 + 1][m][bp] = v.y;
        ins[u0 + 2][m][bp] = v.z;
        ins[u0 + 3][m][bp] = v.w;
    }
    __syncthreads();
    if (tid < Hd)
        mean_s[tid] = (ps[0][tid] + ps[1][tid]) * (1.f / (float)Etot);
    __syncthreads();

    // ---- z for 2 bps: half-split over u; 2 packed loads per u ----
    {
        int r = tid & 127, h = tid >> 7;
        float acc0 = 0.f, acc1 = 0.f, accg = 0.f;
        const unsigned* p1c = p1 + r;
        const unsigned* p2c = p2 + r;
#pragma unroll 4
        for (int u = h * 64; u < h * 64 + 64; ++u) {
            unsigned w1 = p1c[u * Hd];
            unsigned w2 = p2c[u * Hd];
            float wa = __uint_as_float(w1 << 16);
            float wb = __uint_as_float(w1 & 0xffff0000u);
            float wm = __uint_as_float(w2 << 16);
            float wg = __uint_as_float(w2 & 0xffff0000u);
            accg += wg * mean_s[u];
            float lv0 = ins[u][0][0], lv1 = ins[u][0][1];
            float vv0 = ins[u][1][0], vv1 = ins[u][1][1];
            float qv0 = ins[u][2][0], qv1 = ins[u][2][1];
            acc0 += wa * lv0 + wb * vv0 + wm * qv0;
            acc1 += wa * lv1 + wb * vv1 + wm * qv1;
        }
        zpart[h][0][r] = acc0 + accg;
        zpart[h][1][r] = acc1 + accg;
    }
    __syncthreads();
    {
        int bp = tid >> 7, r = tid & 127;
        z_s[bp][r] = zpart[0][bp][r] + zpart[1][bp][r];
    }
    __syncthreads();

    // ---- gather og from emb (L3-hot), copy out, dot with z (proven interleave) ----
    {
        int rg = tid >> 5, c4 = tid & 31;
        for (int bp = 0; bp < 2; ++bp) {
            const float4* ebase = (const float4*)emb + ((size_t)b * Etot + (size_t)lni_s[bp] * Deg) * 32;
            float4* ob = (float4*)out_og + ((size_t)(bp0 + bp)) * (Deg * 32);
            float4 z4 = ((const float4*)z_s[bp])[c4];
#pragma unroll
            for (int r0 = 0; r0 < 4; ++r0) {
                int r = rg + r0 * 8;
                float4 v = ebase[r * 32 + c4];
                ob[r * 32 + c4] = v;
                float part = v.x * z4.x + v.y * z4.y + v.z * z4.z + v.w * z4.w;
                for (int m = 16; m >= 1; m >>= 1)
                    part += __shfl_xor(part, m, 64);
                if (c4 == 0) score_s[bp][r] = part;
            }
        }
    }
    __syncthreads();

    // ---- softmax over Deg for the 2 bps (threads 0..63 = 2x32) ----
    if (tid < 64) {
        float s = score_s[bp_i][d] * 0.011048543456039805f;  // 1/(8*sqrt(128))
        float ds = p0v * dd.x + p1v * dd.y;
        s -= ds * 0.7071067811865476f;                       // /sqrt(2)
        float sc = 10.0f * tanhf(s);
        float m = mval;
        if (isinf(m) && m < 0.f) m = -1.0e8f;
        float v = sc + m;
        float mx = v;
        for (int mm = 16; mm >= 1; mm >>= 1)
            mx = fmaxf(mx, __shfl_xor(mx, mm, 64));
        float e = expf(v - mx);
        float sum = e;
        for (int mm = 16; mm >= 1; mm >>= 1)
            sum += __shfl_xor(sum, mm, 64);
        out_probs[(size_t)(bp0 + bp_i) * Deg + d] = e / sum;
    }
}

extern "C" void kernel_launch(void* const* d_in, const int* in_sizes, int n_in,
                              void* d_out, int out_size, void* d_ws, size_t ws_size,
                              hipStream_t stream) {
    const float* emb       = (const float*)d_in[0];
    const float* dists     = (const float*)d_in[1];
    const float* pref      = (const float*)d_in[2];
    const int*   indices   = (const int*)d_in[3];
    // d_in[4] = Wq_first : unused by the reference
    const float* Wq_last    = (const float*)d_in[5];
    const float* Wq_visited = (const float*)d_in[6];
    const float* Wq_graph   = (const float*)d_in[7];
    const float* Wq         = (const float*)d_in[8];
    const float* Wk         = (const float*)d_in[9];
    const float* q_first    = (const float*)d_in[10];
    const float* visited    = (const float*)d_in[11];
    const float* last_edge  = (const float*)d_in[12];
    const int*   lni        = (const int*)d_in[13];
    const float* gmask      = (const float*)d_in[14];

    float* w = (float*)d_ws;
    float* ws_partial = w;                                         // 16*64*128 floats
    unsigned* ws_p1   = (unsigned*)(w + (size_t)Bsz * CHUNKS * Hd); // 16384 uints
    unsigned* ws_p2   = ws_p1 + Hd * Hd;                           // 16384 uints

    float* out       = (float*)d_out;
    float* out_probs = out;
    float* out_nk    = out + (size_t)Bsz * Pg * Deg;
    float* out_og    = out + 2 * (size_t)Bsz * Pg * Deg;

    fused_all<<<PREP_BLKS + Bsz * CHUNKS, 256, 0, stream>>>(emb, Wq, Wk, Wq_last, Wq_visited,
                                                            Wq_graph, ws_partial, ws_p1, ws_p2);
    decode_z<<<800, 256, 0, stream>>>(ws_partial, ws_p1, ws_p2,
                                      q_first, visited, last_edge, emb, dists, pref,
                                      indices, lni, gmask, out_probs, out_nk, out_og);
}